// Round 2
// baseline (30.846 us; speedup 1.0000x reference)
//
#include <hip/hip_runtime.h>

#define EPS 1e-10f
#define FAR_DELTA 1e10f

// One 64-lane wave per ray; each lane owns 2 consecutive samples.
// S = 128, C = 3 are hard-coded (matches setup_inputs()).
__global__ __launch_bounds__(256) void volrender_kernel(
    const float* __restrict__ density,   // [N,128]
    const float* __restrict__ feature,   // [N,128,3]
    const float* __restrict__ depth,     // [N,128]
    float* __restrict__ out,             // [N,4]
    int N)
{
    const int wave = (blockIdx.x * blockDim.x + threadIdx.x) >> 6;
    const int lane = threadIdx.x & 63;
    if (wave >= N) return;
    const size_t n = (size_t)wave;

    // ---- coalesced loads: 8B per lane per stream ----
    const float2 dd = *(const float2*)(depth   + n * 128 + lane * 2);
    const float2 dn = *(const float2*)(density + n * 128 + lane * 2);
    const float* fb = feature + n * 384 + lane * 6;
    const float2 f01 = *(const float2*)(fb);       // f0.c0, f0.c1
    const float2 f23 = *(const float2*)(fb + 2);   // f0.c2, f1.c0
    const float2 f45 = *(const float2*)(fb + 4);   // f1.c1, f1.c2

    // ---- deltas ----
    const float d_next0 = __shfl_down(dd.x, 1, 64);        // next lane's first depth
    const float delta0 = dd.y - dd.x;
    const float delta1 = (lane == 63) ? FAR_DELTA : (d_next0 - dd.y);

    const float e0 = dn.x * delta0;
    const float e1 = dn.y * delta1;

    // ---- exclusive wave prefix sum ----
    // The last sample's exponent (lane 63's e1 = density*1e10) is only ever
    // used in its own alpha; it must NOT enter the scan (fp32 ulp(1e10)=1024
    // would annihilate the finite prefix).
    const float scan_in = e0 + ((lane == 63) ? 0.0f : e1);
    float x = scan_in;
    #pragma unroll
    for (int off = 1; off < 64; off <<= 1) {
        const float y = __shfl_up(x, off, 64);
        if (lane >= off) x += y;
    }
    // exclusive prefix without subtraction (no cancellation)
    float excl = __shfl_up(x, 1, 64);
    if (lane == 0) excl = 0.0f;

    // ---- transmittance / alpha / weights (replicates reference's +EPS) ----
    const float T0 = expf(EPS - excl);
    const float T1 = expf(EPS - (excl + e0));
    const float a0 = 1.0f - expf(EPS - e0);
    const float a1 = 1.0f - expf(EPS - e1);
    const float w0 = T0 * a0;
    const float w1 = T1 * a1;

    // ---- weighted accumulation ----
    float o0 = w0 * f01.x + w1 * f23.y;
    float o1 = w0 * f01.y + w1 * f45.x;
    float o2 = w0 * f23.x + w1 * f45.y;
    float o3 = w0 * dd.x  + w1 * dd.y;

    // ---- wave reduction ----
    #pragma unroll
    for (int off = 32; off > 0; off >>= 1) {
        o0 += __shfl_xor(o0, off, 64);
        o1 += __shfl_xor(o1, off, 64);
        o2 += __shfl_xor(o2, off, 64);
        o3 += __shfl_xor(o3, off, 64);
    }

    if (lane == 0) {
        *(float4*)(out + n * 4) = make_float4(o0, o1, o2, o3);
    }
}

extern "C" void kernel_launch(void* const* d_in, const int* in_sizes, int n_in,
                              void* d_out, int out_size, void* d_ws, size_t ws_size,
                              hipStream_t stream) {
    const float* density = (const float*)d_in[0];   // [N,128]
    const float* feature = (const float*)d_in[1];   // [N,128,3]
    const float* depth   = (const float*)d_in[2];   // [N,128]
    float* out = (float*)d_out;                     // [N,4]

    const int N = in_sizes[0] / 128;
    const int threads = 256;                 // 4 waves/block -> 4 rays/block
    const int blocks = (N + 3) / 4;
    volrender_kernel<<<blocks, threads, 0, stream>>>(density, feature, depth, out, N);
}

// Round 3
// 30.129 us; speedup vs baseline: 1.0238x; 1.0238x over previous
//
#include <hip/hip_runtime.h>

#define EPS 1e-10f
#define FAR_DELTA 1e10f

// 4 rays per wave: each 16-lane segment owns one ray, 8 samples per lane.
// S = 128, C = 3 hard-coded (matches setup_inputs()).
__global__ __launch_bounds__(256) void volrender_kernel(
    const float* __restrict__ density,   // [N,128]
    const float* __restrict__ feature,   // [N,128,3]
    const float* __restrict__ depth,     // [N,128]
    float* __restrict__ out,             // [N,4]
    int N)
{
    const int wave = (blockIdx.x * blockDim.x + threadIdx.x) >> 6;
    const int lane = threadIdx.x & 63;
    const int sub  = lane & 15;          // lane within the ray's 16-lane segment
    const int rloc = lane >> 4;          // which of the wave's 4 rays
    int n = wave * 4 + rloc;
    const bool valid = (n < N);
    if (!valid) n = 0;                   // harmless loads; store is guarded

    const float* dp = depth   + (size_t)n * 128 + sub * 8;
    const float* sp = density + (size_t)n * 128 + sub * 8;
    const float* fp = feature + (size_t)n * 384 + sub * 24;

    // ---- coalesced float4 loads (16B/lane) ----
    const float4 d0 = *(const float4*)(dp);
    const float4 d1 = *(const float4*)(dp + 4);
    const float4 s0 = *(const float4*)(sp);
    const float4 s1 = *(const float4*)(sp + 4);
    const float4 fA = *(const float4*)(fp);
    const float4 fB = *(const float4*)(fp + 4);
    const float4 fC = *(const float4*)(fp + 8);
    const float4 fD = *(const float4*)(fp + 12);
    const float4 fE = *(const float4*)(fp + 16);
    const float4 fF = *(const float4*)(fp + 20);

    float d[8] = {d0.x, d0.y, d0.z, d0.w, d1.x, d1.y, d1.z, d1.w};
    float s[8] = {s0.x, s0.y, s0.z, s0.w, s1.x, s1.y, s1.z, s1.w};
    const float f[8][3] = {
        {fA.x, fA.y, fA.z}, {fA.w, fB.x, fB.y},
        {fB.z, fB.w, fC.x}, {fC.y, fC.z, fC.w},
        {fD.x, fD.y, fD.z}, {fD.w, fE.x, fE.y},
        {fE.z, fE.w, fF.x}, {fF.y, fF.z, fF.w}};

    // ---- deltas & exponents ----
    const float dnext = __shfl_down(d[0], 1, 64);  // next lane's first depth
    float e[8];
    #pragma unroll
    for (int j = 0; j < 7; ++j) e[j] = s[j] * (d[j + 1] - d[j]);
    e[7] = s[7] * ((sub == 15) ? FAR_DELTA : (dnext - d[7]));

    // Global last sample's exponent (density*1e10) must NOT enter the scan:
    // fp32 ulp(1e10)=1024 would annihilate the finite prefix.
    const float local = e[0] + e[1] + e[2] + e[3] + e[4] + e[5] + e[6]
                      + ((sub == 15) ? 0.0f : e[7]);

    // ---- segmented (width=16) inclusive scan ----
    float x = local;
    #pragma unroll
    for (int off = 1; off < 16; off <<= 1) {
        const float y = __shfl_up(x, off, 16);
        if (sub >= off) x += y;
    }
    float excl = __shfl_up(x, 1, 16);
    if (sub == 0) excl = 0.0f;

    // ---- per-sample weights + accumulation (all statically unrolled) ----
    float c = excl;
    float o0 = 0.f, o1 = 0.f, o2 = 0.f, o3 = 0.f;
    #pragma unroll
    for (int j = 0; j < 8; ++j) {
        const float T = expf(EPS - c);
        const float a = 1.0f - expf(EPS - e[j]);
        const float w = T * a;
        o0 += w * f[j][0];
        o1 += w * f[j][1];
        o2 += w * f[j][2];
        o3 += w * d[j];
        c += e[j];
    }

    // ---- segmented (width=16) butterfly reduction ----
    #pragma unroll
    for (int off = 1; off < 16; off <<= 1) {
        o0 += __shfl_xor(o0, off, 16);
        o1 += __shfl_xor(o1, off, 16);
        o2 += __shfl_xor(o2, off, 16);
        o3 += __shfl_xor(o3, off, 16);
    }

    if (sub == 0 && valid) {
        *(float4*)(out + (size_t)n * 4) = make_float4(o0, o1, o2, o3);
    }
}

extern "C" void kernel_launch(void* const* d_in, const int* in_sizes, int n_in,
                              void* d_out, int out_size, void* d_ws, size_t ws_size,
                              hipStream_t stream) {
    const float* density = (const float*)d_in[0];   // [N,128]
    const float* feature = (const float*)d_in[1];   // [N,128,3]
    const float* depth   = (const float*)d_in[2];   // [N,128]
    float* out = (float*)d_out;                     // [N,4]

    const int N = in_sizes[0] / 128;
    const int threads = 256;                 // 4 waves/block, 4 rays/wave
    const int blocks = (N + 15) / 16;        // 16 rays/block
    volrender_kernel<<<blocks, threads, 0, stream>>>(density, feature, depth, out, N);
}